// Round 3
// baseline (124.894 us; speedup 1.0000x reference)
//
#include <hip/hip_runtime.h>
#include <hip/hip_bf16.h>

using bf16 = __hip_bfloat16;
typedef __attribute__((ext_vector_type(8))) short frag_ab;   // 8 bf16
typedef __attribute__((ext_vector_type(4))) float frag_cd;   // 4 fp32

constexpr float TEMP   = 0.07f;
constexpr float INVT   = 1.0f / TEMP;                 // fixed logsumexp shift
constexpr float THRESH = 0.1f;
constexpr float EPS    = 1e-8f;
constexpr float LOG2E  = 1.4426950408889634f;
constexpr float C1     = LOG2E / TEMP;                // exp((s-1)/T) = exp2(s*C1 - C1)

constexpr int D      = 128;
constexpr int SPLITS = 16;    // column splits -> grid (64,16) = 1024 blocks, 4/CU
constexpr int TI     = 128;   // rows per block (4 waves x 32 rows)
constexpr int TJ     = 64;    // cols per LDS tile

__device__ __forceinline__ frag_cd mfma16(frag_ab a, frag_ab b, frag_cd c) {
    return __builtin_amdgcn_mfma_f32_16x16x32_bf16(a, b, c, 0, 0, 0);
}

// ---------------- kernel 1: row-normalize, cast to bf16, emit diagonal dot ----------------
__global__ __launch_bounds__(256) void k1_normalize(
    const float* __restrict__ f, bf16* __restrict__ fn,
    float* __restrict__ diag, int n)
{
    const int row  = blockIdx.x * 4 + (threadIdx.x >> 6);
    const int lane = threadIdx.x & 63;
    float2 v = ((const float2*)(f + (size_t)row * D))[lane];
    float ss = v.x * v.x + v.y * v.y;
    #pragma unroll
    for (int m = 32; m >= 1; m >>= 1) ss += __shfl_xor(ss, m, 64);
    const float inv = 1.0f / fmaxf(sqrtf(ss), EPS);
    __hip_bfloat162 o;
    o.x = __float2bfloat16(v.x * inv);
    o.y = __float2bfloat16(v.y * inv);
    ((__hip_bfloat162*)(fn + (size_t)row * D))[lane] = o;
    // diagonal raw dot of the bf16-rounded row (matches MFMA s_ii to ~1e-6)
    const float a = __bfloat162float(o.x), b = __bfloat162float(o.y);
    float p = a * a + b * b;
    #pragma unroll
    for (int m = 32; m >= 1; m >>= 1) p += __shfl_xor(p, m, 64);
    if (lane == 0) diag[row] = p;
}

// ---------------- kernel 2: fused sim + masked reductions ----------------
// grid = (n/TI, SPLITS), block = 256. Wave w owns rows [TI*bx + 32w, +32) as two
// 16-row A-fragment sets; B tile (TJ cols x 128) staged in XOR-swizzled LDS so
// each 4x ds_read_b128 B-fragment feeds 8 MFMAs (2 row-sets).
__global__ __launch_bounds__(256, 4) void k2_main(
    const bf16* __restrict__ fn, const float* __restrict__ lab,
    float* __restrict__ se_p, float* __restrict__ sp_p,
    float* __restrict__ cnt_p, int n)
{
    __shared__ float lab_s[512];          // cps = 8192/16
    __shared__ bf16  colbuf[TJ * D];      // swizzled: [(c*128) + ((chunk ^ (c&15))*8)]

    const int tid  = threadIdx.x;
    const int wave = tid >> 6;
    const int lane = tid & 63;
    const int quad = lane >> 4;
    const int l15  = lane & 15;

    const int cps    = n / SPLITS;        // 512
    const int cbase0 = blockIdx.y * cps;
    const int row_base = blockIdx.x * TI + wave * 32;

    for (int i = tid; i < cps; i += 256) lab_s[i] = lab[cbase0 + i];

    // A fragments: set s covers rows row_base + s*16 + l15, k = kb*32 + quad*8 + j
    frag_ab afr[2][4];
    #pragma unroll
    for (int s = 0; s < 2; ++s) {
        const bf16* ap = fn + (size_t)(row_base + s * 16 + l15) * D + quad * 8;
        #pragma unroll
        for (int kb = 0; kb < 4; ++kb) afr[s][kb] = *(const frag_ab*)(ap + kb * 32);
    }
    float li[2][4];
    #pragma unroll
    for (int s = 0; s < 2; ++s)
        #pragma unroll
        for (int r = 0; r < 4; ++r)
            li[s][r] = lab[row_base + s * 16 + quad * 4 + r];

    float se[2][4] = {}, sp[2][4] = {}, cnt[2][4] = {};

    const int c0    = tid >> 4;   // 0..15 (staging column within 16-col group)
    const int chunk = tid & 15;   // 16B chunk within a column
    const int ntiles = cps / TJ;  // 8

    // software pipeline: prefetch tile 0 into registers
    frag_ab st[4];
    {
        const bf16* gp = fn + (size_t)(cbase0 + c0) * D + chunk * 8;
        #pragma unroll
        for (int cc = 0; cc < 4; ++cc)
            st[cc] = *(const frag_ab*)(gp + (size_t)cc * 16 * D);
    }

    for (int jt = 0; jt < ntiles; ++jt) {
        __syncthreads();   // previous tile's readers done
        #pragma unroll
        for (int cc = 0; cc < 4; ++cc)
            *(frag_ab*)(&colbuf[(size_t)(cc * 16 + c0) * D + ((chunk ^ c0) * 8)]) = st[cc];
        if (jt + 1 < ntiles) {   // issue next tile's global loads; latency hidden by compute
            const bf16* gp = fn + (size_t)(cbase0 + (jt + 1) * TJ + c0) * D + chunk * 8;
            #pragma unroll
            for (int cc = 0; cc < 4; ++cc)
                st[cc] = *(const frag_ab*)(gp + (size_t)cc * 16 * D);
        }
        __syncthreads();   // staging visible

        #pragma unroll
        for (int sub = 0; sub < 4; ++sub) {
            const int c = sub * 16 + l15;          // column within tile
            frag_ab b[4];
            #pragma unroll
            for (int kb = 0; kb < 4; ++kb)
                b[kb] = *(const frag_ab*)(&colbuf[(size_t)c * D + (((quad + 4 * kb) ^ l15) * 8)]);
            frag_cd a0 = {0.f, 0.f, 0.f, 0.f}, a1 = {0.f, 0.f, 0.f, 0.f};
            #pragma unroll
            for (int kb = 0; kb < 4; ++kb) {
                a0 = mfma16(afr[0][kb], b[kb], a0);
                a1 = mfma16(afr[1][kb], b[kb], a1);
            }
            const float lj = lab_s[jt * TJ + c];
            #pragma unroll
            for (int s = 0; s < 2; ++s) {
                const frag_cd& acc = s ? a1 : a0;
                #pragma unroll
                for (int r = 0; r < 4; ++r) {
                    const float sv = acc[r];                      // raw dot (cosine)
                    const float e  = __builtin_amdgcn_exp2f(__builtin_fmaf(sv, C1, -C1));
                    const float pm = (fabsf(li[s][r] - lj) < THRESH) ? 1.0f : 0.0f;
                    se[s][r]  += e;
                    sp[s][r]   = __builtin_fmaf(pm, sv, sp[s][r]); // raw dots; 1/T in k3
                    cnt[s][r] += pm;
                }
            }
        }
    }

    // reduce across the 16 lanes of each quad-group (same rows, cols mod 16)
    #pragma unroll
    for (int s = 0; s < 2; ++s)
        #pragma unroll
        for (int r = 0; r < 4; ++r) {
            #pragma unroll
            for (int m = 1; m < 16; m <<= 1) {
                se[s][r]  += __shfl_xor(se[s][r],  m, 64);
                sp[s][r]  += __shfl_xor(sp[s][r],  m, 64);
                cnt[s][r] += __shfl_xor(cnt[s][r], m, 64);
            }
        }
    if (l15 == 0) {
        #pragma unroll
        for (int s = 0; s < 2; ++s)
            #pragma unroll
            for (int r = 0; r < 4; ++r) {
                const int i = row_base + s * 16 + quad * 4 + r;
                se_p[(size_t)blockIdx.y * n + i]  = se[s][r];
                sp_p[(size_t)blockIdx.y * n + i]  = sp[s][r];
                cnt_p[(size_t)blockIdx.y * n + i] = cnt[s][r];
            }
    }
}

// ---------------- kernel 3: per-row finalize (elementwise, coalesced) ----------------
__global__ __launch_bounds__(256) void k3_finalize(
    const float* __restrict__ diag, const float* __restrict__ se_p,
    const float* __restrict__ sp_p, const float* __restrict__ cnt_p,
    float* __restrict__ loss_row, int n)
{
    const int row = blockIdx.x * 256 + threadIdx.x;
    float se = 0.f, sp = 0.f, cnt = 0.f;
    #pragma unroll
    for (int s = 0; s < SPLITS; ++s) {
        se  += se_p[(size_t)s * n + row];
        sp  += sp_p[(size_t)s * n + row];
        cnt += cnt_p[(size_t)s * n + row];
    }
    const float s_ii = diag[row];
    se  -= __builtin_amdgcn_exp2f(__builtin_fmaf(s_ii, C1, -C1));
    sp  -= s_ii;
    cnt -= 1.0f;
    loss_row[row] = INVT + __logf(se) - (sp * INVT) / fmaxf(cnt, 1.0f);
}

// ---------------- kernel 4: single-block mean reduction ----------------
__global__ __launch_bounds__(256) void k4_reduce(
    const float* __restrict__ loss_row, float* __restrict__ out, int n)
{
    float s = 0.f;
    for (int i = threadIdx.x; i < n; i += 256) s += loss_row[i];
    #pragma unroll
    for (int m = 32; m >= 1; m >>= 1) s += __shfl_xor(s, m, 64);
    __shared__ float wsum[4];
    if ((threadIdx.x & 63) == 0) wsum[threadIdx.x >> 6] = s;
    __syncthreads();
    if (threadIdx.x == 0)
        out[0] = (wsum[0] + wsum[1] + wsum[2] + wsum[3]) / (float)n;
}

extern "C" void kernel_launch(void* const* d_in, const int* in_sizes, int n_in,
                              void* d_out, int out_size, void* d_ws, size_t ws_size,
                              hipStream_t stream) {
    const float* feat = (const float*)d_in[0];
    const float* lab  = (const float*)d_in[1];
    const int n = in_sizes[1];              // 8192
    float* out = (float*)d_out;

    // ws: fn (n*D bf16 = 2MB) | diag | se_p | sp_p | cnt_p (each SPLITS*n f32) | loss_row
    char* ws = (char*)d_ws;
    bf16* fn = (bf16*)ws;
    size_t off = (size_t)n * D * sizeof(bf16);
    float* diag  = (float*)(ws + off); off += (size_t)n * sizeof(float);
    float* se_p  = (float*)(ws + off); off += (size_t)SPLITS * n * sizeof(float);
    float* sp_p  = (float*)(ws + off); off += (size_t)SPLITS * n * sizeof(float);
    float* cnt_p = (float*)(ws + off); off += (size_t)SPLITS * n * sizeof(float);
    float* loss_row = (float*)(ws + off);

    k1_normalize<<<n / 4, 256, 0, stream>>>(feat, fn, diag, n);
    dim3 g2(n / TI, SPLITS);
    k2_main<<<g2, 256, 0, stream>>>(fn, lab, se_p, sp_p, cnt_p, n);
    k3_finalize<<<n / 256, 256, 0, stream>>>(diag, se_p, sp_p, cnt_p, loss_row, n);
    k4_reduce<<<1, 256, 0, stream>>>(loss_row, out, n);
}

// Round 4
// 98.004 us; speedup vs baseline: 1.2744x; 1.2744x over previous
//
#include <hip/hip_runtime.h>
#include <hip/hip_bf16.h>

using bf16 = __hip_bfloat16;
typedef __attribute__((ext_vector_type(8))) short frag_ab;   // 8 bf16
typedef __attribute__((ext_vector_type(4))) float frag_cd;   // 4 fp32

constexpr float TEMP   = 0.07f;
constexpr float INVT   = 1.0f / TEMP;                 // fixed logsumexp shift
constexpr float THRESH = 0.1f;
constexpr float EPS    = 1e-8f;
constexpr float LOG2E  = 1.4426950408889634f;
constexpr float C1     = LOG2E / TEMP;                // exp((s-1)/T) = exp2(s*C1 - C1)

constexpr int D      = 128;
constexpr int SPLITS = 16;    // column splits -> grid (64,16) = 1024 blocks
constexpr int TI     = 128;   // rows per block (4 waves x 32 rows)
constexpr int TJ     = 64;    // cols per LDS tile

__device__ __forceinline__ frag_cd mfma16(frag_ab a, frag_ab b, frag_cd c) {
    return __builtin_amdgcn_mfma_f32_16x16x32_bf16(a, b, c, 0, 0, 0);
}

// ---------------- kernel 1: row-normalize, cast to bf16, emit diagonal dot ----------------
__global__ __launch_bounds__(256) void k1_normalize(
    const float* __restrict__ f, bf16* __restrict__ fn,
    float* __restrict__ diag, int n)
{
    const int row  = blockIdx.x * 4 + (threadIdx.x >> 6);
    const int lane = threadIdx.x & 63;
    float2 v = ((const float2*)(f + (size_t)row * D))[lane];
    float ss = v.x * v.x + v.y * v.y;
    #pragma unroll
    for (int m = 32; m >= 1; m >>= 1) ss += __shfl_xor(ss, m, 64);
    const float inv = 1.0f / fmaxf(sqrtf(ss), EPS);
    __hip_bfloat162 o;
    o.x = __float2bfloat16(v.x * inv);
    o.y = __float2bfloat16(v.y * inv);
    ((__hip_bfloat162*)(fn + (size_t)row * D))[lane] = o;
    // diagonal raw dot of the bf16-rounded row (matches MFMA s_ii to ~1e-6)
    const float a = __bfloat162float(o.x), b = __bfloat162float(o.y);
    float p = a * a + b * b;
    #pragma unroll
    for (int m = 32; m >= 1; m >>= 1) p += __shfl_xor(p, m, 64);
    if (lane == 0) diag[row] = p;
}

// ---------------- kernel 2: fused sim + masked reductions ----------------
// grid = (n/TI, SPLITS), block = 256. Wave w owns rows [TI*bx + 32w, +32) as two
// 16-row A-fragment sets; B tile (TJ cols x 128) staged in XOR-swizzled LDS
// (0 bank conflicts, verified R3); each B-fragment read feeds 8 MFMAs.
// NOTE: no register prefetch — R3 showed it spills (~512 B/thread scratch,
// 150 MB HBM writes). launch_bounds(256,3): VGPR cap ~170, fits ~130 live.
__global__ __launch_bounds__(256, 3) void k2_main(
    const bf16* __restrict__ fn, const float* __restrict__ lab,
    float* __restrict__ se_p, float* __restrict__ sp_p,
    float* __restrict__ cnt_p, int n)
{
    __shared__ float lab_s[512];          // cps = 8192/16
    __shared__ bf16  colbuf[TJ * D];      // swizzled: [(c*128) + ((chunk ^ (c&15))*8)]

    const int tid  = threadIdx.x;
    const int wave = tid >> 6;
    const int lane = tid & 63;
    const int quad = lane >> 4;
    const int l15  = lane & 15;

    const int cps    = n / SPLITS;        // 512
    const int cbase0 = blockIdx.y * cps;
    const int row_base = blockIdx.x * TI + wave * 32;

    for (int i = tid; i < cps; i += 256) lab_s[i] = lab[cbase0 + i];

    // A fragments: set s covers rows row_base + s*16 + l15, k = kb*32 + quad*8 + j
    frag_ab afr[2][4];
    #pragma unroll
    for (int s = 0; s < 2; ++s) {
        const bf16* ap = fn + (size_t)(row_base + s * 16 + l15) * D + quad * 8;
        #pragma unroll
        for (int kb = 0; kb < 4; ++kb) afr[s][kb] = *(const frag_ab*)(ap + kb * 32);
    }
    float li[2][4];
    #pragma unroll
    for (int s = 0; s < 2; ++s)
        #pragma unroll
        for (int r = 0; r < 4; ++r)
            li[s][r] = lab[row_base + s * 16 + quad * 4 + r];

    float se[2][4] = {}, sp[2][4] = {}, cnt[2][4] = {};

    const int c0    = tid >> 4;   // 0..15 (staging column within 16-col group)
    const int chunk = tid & 15;   // 16B chunk within a column
    const int ntiles = cps / TJ;  // 8
    // staggered start: desynchronize the barrier convoy across co-resident
    // blocks and spread L2 reads of fn across different tiles
    const int jt0 = (blockIdx.x + blockIdx.y) & (ntiles - 1);

    for (int t = 0; t < ntiles; ++t) {
        const int jt = (jt0 + t) & (ntiles - 1);
        __syncthreads();   // previous tile's readers done
        {   // stage TJ cols x 128 bf16 directly (global -> VGPR -> swizzled LDS)
            const bf16* gp = fn + (size_t)(cbase0 + jt * TJ + c0) * D + chunk * 8;
            #pragma unroll
            for (int cc = 0; cc < 4; ++cc) {
                frag_ab v = *(const frag_ab*)(gp + (size_t)cc * 16 * D);
                *(frag_ab*)(&colbuf[(size_t)(cc * 16 + c0) * D + ((chunk ^ c0) * 8)]) = v;
            }
        }
        __syncthreads();   // staging visible

        #pragma unroll
        for (int sub = 0; sub < 4; ++sub) {
            const int c = sub * 16 + l15;          // column within tile
            frag_ab b[4];
            #pragma unroll
            for (int kb = 0; kb < 4; ++kb)
                b[kb] = *(const frag_ab*)(&colbuf[(size_t)c * D + (((quad + 4 * kb) ^ l15) * 8)]);
            frag_cd a0 = {0.f, 0.f, 0.f, 0.f}, a1 = {0.f, 0.f, 0.f, 0.f};
            #pragma unroll
            for (int kb = 0; kb < 4; ++kb) {
                a0 = mfma16(afr[0][kb], b[kb], a0);
                a1 = mfma16(afr[1][kb], b[kb], a1);
            }
            const float lj = lab_s[jt * TJ + c];
            #pragma unroll
            for (int s = 0; s < 2; ++s) {
                const frag_cd& acc = s ? a1 : a0;
                #pragma unroll
                for (int r = 0; r < 4; ++r) {
                    const float sv = acc[r];                      // raw dot (cosine)
                    const float e  = __builtin_amdgcn_exp2f(__builtin_fmaf(sv, C1, -C1));
                    const float pm = (fabsf(li[s][r] - lj) < THRESH) ? 1.0f : 0.0f;
                    se[s][r]  += e;
                    sp[s][r]   = __builtin_fmaf(pm, sv, sp[s][r]); // raw dots; 1/T in k3
                    cnt[s][r] += pm;
                }
            }
        }
    }

    // reduce across the 16 lanes of each quad-group (same rows, cols mod 16)
    #pragma unroll
    for (int s = 0; s < 2; ++s)
        #pragma unroll
        for (int r = 0; r < 4; ++r) {
            #pragma unroll
            for (int m = 1; m < 16; m <<= 1) {
                se[s][r]  += __shfl_xor(se[s][r],  m, 64);
                sp[s][r]  += __shfl_xor(sp[s][r],  m, 64);
                cnt[s][r] += __shfl_xor(cnt[s][r], m, 64);
            }
        }
    if (l15 == 0) {
        #pragma unroll
        for (int s = 0; s < 2; ++s)
            #pragma unroll
            for (int r = 0; r < 4; ++r) {
                const int i = row_base + s * 16 + quad * 4 + r;
                se_p[(size_t)blockIdx.y * n + i]  = se[s][r];
                sp_p[(size_t)blockIdx.y * n + i]  = sp[s][r];
                cnt_p[(size_t)blockIdx.y * n + i] = cnt[s][r];
            }
    }
}

// ---------------- kernel 3: per-row finalize (elementwise, coalesced) ----------------
__global__ __launch_bounds__(256) void k3_finalize(
    const float* __restrict__ diag, const float* __restrict__ se_p,
    const float* __restrict__ sp_p, const float* __restrict__ cnt_p,
    float* __restrict__ loss_row, int n)
{
    const int row = blockIdx.x * 256 + threadIdx.x;
    float se = 0.f, sp = 0.f, cnt = 0.f;
    #pragma unroll
    for (int s = 0; s < SPLITS; ++s) {
        se  += se_p[(size_t)s * n + row];
        sp  += sp_p[(size_t)s * n + row];
        cnt += cnt_p[(size_t)s * n + row];
    }
    const float s_ii = diag[row];
    se  -= __builtin_amdgcn_exp2f(__builtin_fmaf(s_ii, C1, -C1));
    sp  -= s_ii;
    cnt -= 1.0f;
    loss_row[row] = INVT + __logf(se) - (sp * INVT) / fmaxf(cnt, 1.0f);
}

// ---------------- kernel 4: single-block mean reduction ----------------
__global__ __launch_bounds__(1024) void k4_reduce(
    const float* __restrict__ loss_row, float* __restrict__ out, int n)
{
    float s = 0.f;
    for (int i = threadIdx.x; i < n; i += 1024) s += loss_row[i];
    #pragma unroll
    for (int m = 32; m >= 1; m >>= 1) s += __shfl_xor(s, m, 64);
    __shared__ float wsum[16];
    if ((threadIdx.x & 63) == 0) wsum[threadIdx.x >> 6] = s;
    __syncthreads();
    if (threadIdx.x == 0) {
        float tot = 0.f;
        #pragma unroll
        for (int w = 0; w < 16; ++w) tot += wsum[w];
        out[0] = tot / (float)n;
    }
}

extern "C" void kernel_launch(void* const* d_in, const int* in_sizes, int n_in,
                              void* d_out, int out_size, void* d_ws, size_t ws_size,
                              hipStream_t stream) {
    const float* feat = (const float*)d_in[0];
    const float* lab  = (const float*)d_in[1];
    const int n = in_sizes[1];              // 8192
    float* out = (float*)d_out;

    // ws: fn (n*D bf16 = 2MB) | diag | se_p | sp_p | cnt_p (each SPLITS*n f32) | loss_row
    char* ws = (char*)d_ws;
    bf16* fn = (bf16*)ws;
    size_t off = (size_t)n * D * sizeof(bf16);
    float* diag  = (float*)(ws + off); off += (size_t)n * sizeof(float);
    float* se_p  = (float*)(ws + off); off += (size_t)SPLITS * n * sizeof(float);
    float* sp_p  = (float*)(ws + off); off += (size_t)SPLITS * n * sizeof(float);
    float* cnt_p = (float*)(ws + off); off += (size_t)SPLITS * n * sizeof(float);
    float* loss_row = (float*)(ws + off);

    k1_normalize<<<n / 4, 256, 0, stream>>>(feat, fn, diag, n);
    dim3 g2(n / TI, SPLITS);
    k2_main<<<g2, 256, 0, stream>>>(fn, lab, se_p, sp_p, cnt_p, n);
    k3_finalize<<<n / 256, 256, 0, stream>>>(diag, se_p, sp_p, cnt_p, loss_row, n);
    k4_reduce<<<1, 1024, 0, stream>>>(loss_row, out, n);
}

// Round 5
// 93.559 us; speedup vs baseline: 1.3349x; 1.0475x over previous
//
#include <hip/hip_runtime.h>
#include <hip/hip_bf16.h>

using bf16 = __hip_bfloat16;
typedef __attribute__((ext_vector_type(8))) short frag_ab;   // 8 bf16
typedef __attribute__((ext_vector_type(4))) float frag_cd;   // 4 fp32

constexpr float TEMP   = 0.07f;
constexpr float INVT   = 1.0f / TEMP;                 // fixed logsumexp shift
constexpr float THRESH = 0.1f;
constexpr float EPS    = 1e-8f;
constexpr float LOG2E  = 1.4426950408889634f;
constexpr float C1     = LOG2E / TEMP;                // exp((s-1)/T) = exp2(s*C1 - C1)

constexpr int D      = 128;
constexpr int SPLITS = 16;    // column splits -> grid (64,16) = 1024 blocks
constexpr int TI     = 128;   // rows per block (4 waves x 32 rows)
constexpr int TJ     = 64;    // cols per LDS tile

__device__ __forceinline__ frag_cd mfma16(frag_ab a, frag_ab b, frag_cd c) {
    return __builtin_amdgcn_mfma_f32_16x16x32_bf16(a, b, c, 0, 0, 0);
}

// ------- kernel 1: row-normalize -> bf16, diagonal dot, zero-init reduction cells -------
__global__ __launch_bounds__(256) void k1_normalize(
    const float* __restrict__ f, bf16* __restrict__ fn,
    float* __restrict__ diag, float* __restrict__ acc,
    unsigned* __restrict__ counter, int n)
{
    if (blockIdx.x == 0 && threadIdx.x == 0) { acc[0] = 0.f; counter[0] = 0u; }
    const int row  = blockIdx.x * 4 + (threadIdx.x >> 6);
    const int lane = threadIdx.x & 63;
    float2 v = ((const float2*)(f + (size_t)row * D))[lane];
    float ss = v.x * v.x + v.y * v.y;
    #pragma unroll
    for (int m = 32; m >= 1; m >>= 1) ss += __shfl_xor(ss, m, 64);
    const float inv = 1.0f / fmaxf(sqrtf(ss), EPS);
    __hip_bfloat162 o;
    o.x = __float2bfloat16(v.x * inv);
    o.y = __float2bfloat16(v.y * inv);
    ((__hip_bfloat162*)(fn + (size_t)row * D))[lane] = o;
    // diagonal raw dot of the bf16-rounded row (matches MFMA s_ii to ~1e-6)
    const float a = __bfloat162float(o.x), b = __bfloat162float(o.y);
    float p = a * a + b * b;
    #pragma unroll
    for (int m = 32; m >= 1; m >>= 1) p += __shfl_xor(p, m, 64);
    if (lane == 0) diag[row] = p;
}

// ---------------- kernel 2: fused sim + masked reductions ----------------
// grid = (n/TI, SPLITS), block = 256. Wave w owns rows [TI*bx + 32w, +32) as two
// 16-row A-fragment sets; B tile (TJ cols x 128) in XOR-swizzled LDS (0 conflicts,
// verified R3/R4). Double-buffered LDS + register prefetch: next tile's global
// loads are in flight across the whole compute phase; ONE barrier per tile.
// (256,3): VGPR cap ~170 fits ~150 live incl. 16 prefetch regs — no spill (R3 lesson).
__global__ __launch_bounds__(256, 3) void k2_main(
    const bf16* __restrict__ fn, const float* __restrict__ lab,
    float* __restrict__ se_p, float* __restrict__ sp_p,
    float* __restrict__ cnt_p, int n)
{
    __shared__ float lab_s[512];             // cps = 8192/16
    __shared__ bf16  colbuf[2][TJ * D];      // swizzled: [(c*128) + ((chunk ^ (c&15))*8)]

    const int tid  = threadIdx.x;
    const int wave = tid >> 6;
    const int lane = tid & 63;
    const int quad = lane >> 4;
    const int l15  = lane & 15;

    const int cps    = n / SPLITS;        // 512
    const int cbase0 = blockIdx.y * cps;
    const int row_base = blockIdx.x * TI + wave * 32;

    for (int i = tid; i < cps; i += 256) lab_s[i] = lab[cbase0 + i];

    // A fragments: set s covers rows row_base + s*16 + l15, k = kb*32 + quad*8 + j
    frag_ab afr[2][4];
    #pragma unroll
    for (int s = 0; s < 2; ++s) {
        const bf16* ap = fn + (size_t)(row_base + s * 16 + l15) * D + quad * 8;
        #pragma unroll
        for (int kb = 0; kb < 4; ++kb) afr[s][kb] = *(const frag_ab*)(ap + kb * 32);
    }
    float li[2][4];
    #pragma unroll
    for (int s = 0; s < 2; ++s)
        #pragma unroll
        for (int r = 0; r < 4; ++r)
            li[s][r] = lab[row_base + s * 16 + quad * 4 + r];

    float se[2][4] = {}, sp[2][4] = {}, cnt[2][4] = {};

    const int c0    = tid >> 4;   // 0..15 (staging column within 16-col group)
    const int chunk = tid & 15;   // 16B chunk within a column
    const int ntiles = cps / TJ;  // 8
    const int jt0 = (blockIdx.x + blockIdx.y) & (ntiles - 1);  // convoy stagger

    // prologue: tile jt0 -> regs -> buf[0]
    frag_ab st[4];
    {
        const bf16* gp = fn + (size_t)(cbase0 + jt0 * TJ + c0) * D + chunk * 8;
        #pragma unroll
        for (int cc = 0; cc < 4; ++cc)
            st[cc] = *(const frag_ab*)(gp + (size_t)cc * 16 * D);
        #pragma unroll
        for (int cc = 0; cc < 4; ++cc)
            *(frag_ab*)(&colbuf[0][(size_t)(cc * 16 + c0) * D + ((chunk ^ c0) * 8)]) = st[cc];
    }
    __syncthreads();

    for (int t = 0; t < ntiles; ++t) {
        const int cur = t & 1;
        const int jt  = (jt0 + t) & (ntiles - 1);
        // issue next tile's global loads NOW — in flight across the compute phase
        if (t + 1 < ntiles) {
            const int jn = (jt0 + t + 1) & (ntiles - 1);
            const bf16* gp = fn + (size_t)(cbase0 + jn * TJ + c0) * D + chunk * 8;
            #pragma unroll
            for (int cc = 0; cc < 4; ++cc)
                st[cc] = *(const frag_ab*)(gp + (size_t)cc * 16 * D);
        }

        #pragma unroll
        for (int sub = 0; sub < 4; ++sub) {
            const int c = sub * 16 + l15;          // column within tile
            frag_ab b[4];
            #pragma unroll
            for (int kb = 0; kb < 4; ++kb)
                b[kb] = *(const frag_ab*)(&colbuf[cur][(size_t)c * D + (((quad + 4 * kb) ^ l15) * 8)]);
            frag_cd a0 = {0.f, 0.f, 0.f, 0.f}, a1 = {0.f, 0.f, 0.f, 0.f};
            #pragma unroll
            for (int kb = 0; kb < 4; ++kb) {
                a0 = mfma16(afr[0][kb], b[kb], a0);
                a1 = mfma16(afr[1][kb], b[kb], a1);
            }
            const float lj = lab_s[jt * TJ + c];
            #pragma unroll
            for (int s = 0; s < 2; ++s) {
                const frag_cd& acc = s ? a1 : a0;
                #pragma unroll
                for (int r = 0; r < 4; ++r) {
                    const float sv = acc[r];                      // raw dot (cosine)
                    const float e  = __builtin_amdgcn_exp2f(__builtin_fmaf(sv, C1, -C1));
                    const float pm = (fabsf(li[s][r] - lj) < THRESH) ? 1.0f : 0.0f;
                    se[s][r]  += e;
                    sp[s][r]   = __builtin_fmaf(pm, sv, sp[s][r]); // raw dots; 1/T in k3
                    cnt[s][r] += pm;
                }
            }
        }

        // write prefetched tile into the other buffer, then the single barrier
        if (t + 1 < ntiles) {
            #pragma unroll
            for (int cc = 0; cc < 4; ++cc)
                *(frag_ab*)(&colbuf[cur ^ 1][(size_t)(cc * 16 + c0) * D + ((chunk ^ c0) * 8)]) = st[cc];
        }
        __syncthreads();
    }

    // reduce across the 16 lanes of each quad-group (same rows, cols mod 16)
    #pragma unroll
    for (int s = 0; s < 2; ++s)
        #pragma unroll
        for (int r = 0; r < 4; ++r) {
            #pragma unroll
            for (int m = 1; m < 16; m <<= 1) {
                se[s][r]  += __shfl_xor(se[s][r],  m, 64);
                sp[s][r]  += __shfl_xor(sp[s][r],  m, 64);
                cnt[s][r] += __shfl_xor(cnt[s][r], m, 64);
            }
        }
    if (l15 == 0) {
        #pragma unroll
        for (int s = 0; s < 2; ++s)
            #pragma unroll
            for (int r = 0; r < 4; ++r) {
                const int i = row_base + s * 16 + quad * 4 + r;
                se_p[(size_t)blockIdx.y * n + i]  = se[s][r];
                sp_p[(size_t)blockIdx.y * n + i]  = sp[s][r];
                cnt_p[(size_t)blockIdx.y * n + i] = cnt[s][r];
            }
    }
}

// ------- kernel 3: per-row finalize + grid reduction (last-block pattern) -------
__global__ __launch_bounds__(256) void k3_finalize(
    const float* __restrict__ diag, const float* __restrict__ se_p,
    const float* __restrict__ sp_p, const float* __restrict__ cnt_p,
    float* __restrict__ acc, unsigned* __restrict__ counter,
    float* __restrict__ out, int n)
{
    const int row = blockIdx.x * 256 + threadIdx.x;
    float se = 0.f, sp = 0.f, cnt = 0.f;
    #pragma unroll
    for (int s = 0; s < SPLITS; ++s) {
        se  += se_p[(size_t)s * n + row];
        sp  += sp_p[(size_t)s * n + row];
        cnt += cnt_p[(size_t)s * n + row];
    }
    const float s_ii = diag[row];
    se  -= __builtin_amdgcn_exp2f(__builtin_fmaf(s_ii, C1, -C1));
    sp  -= s_ii;
    cnt -= 1.0f;
    float loss = INVT + __logf(se) - (sp * INVT) / fmaxf(cnt, 1.0f);

    // block reduce
    #pragma unroll
    for (int m = 32; m >= 1; m >>= 1) loss += __shfl_xor(loss, m, 64);
    __shared__ float wsum[4];
    if ((threadIdx.x & 63) == 0) wsum[threadIdx.x >> 6] = loss;
    __syncthreads();
    if (threadIdx.x == 0) {
        const float bs = wsum[0] + wsum[1] + wsum[2] + wsum[3];
        atomicAdd(acc, bs);
        __threadfence();
        const unsigned old = atomicAdd(counter, 1u);
        if (old == gridDim.x - 1) {
            const float total = atomicAdd(acc, 0.0f);  // atomic load, same-address order
            out[0] = total / (float)n;
        }
    }
}

extern "C" void kernel_launch(void* const* d_in, const int* in_sizes, int n_in,
                              void* d_out, int out_size, void* d_ws, size_t ws_size,
                              hipStream_t stream) {
    const float* feat = (const float*)d_in[0];
    const float* lab  = (const float*)d_in[1];
    const int n = in_sizes[1];              // 8192
    float* out = (float*)d_out;

    // ws: fn (n*D bf16 = 2MB) | diag | se_p | sp_p | cnt_p (each SPLITS*n f32) | acc | counter
    char* ws = (char*)d_ws;
    bf16* fn = (bf16*)ws;
    size_t off = (size_t)n * D * sizeof(bf16);
    float* diag  = (float*)(ws + off); off += (size_t)n * sizeof(float);
    float* se_p  = (float*)(ws + off); off += (size_t)SPLITS * n * sizeof(float);
    float* sp_p  = (float*)(ws + off); off += (size_t)SPLITS * n * sizeof(float);
    float* cnt_p = (float*)(ws + off); off += (size_t)SPLITS * n * sizeof(float);
    float* acc   = (float*)(ws + off); off += sizeof(float);
    unsigned* counter = (unsigned*)(ws + off);

    k1_normalize<<<n / 4, 256, 0, stream>>>(feat, fn, diag, acc, counter, n);
    dim3 g2(n / TI, SPLITS);
    k2_main<<<g2, 256, 0, stream>>>(fn, lab, se_p, sp_p, cnt_p, n);
    k3_finalize<<<n / 256, 256, 0, stream>>>(diag, se_p, sp_p, cnt_p, acc, counter, out, n);
}